// Round 4
// baseline (440.999 us; speedup 1.0000x reference)
//
#include <hip/hip_runtime.h>
#include <hip/hip_bf16.h>

typedef unsigned short u16;
typedef __attribute__((ext_vector_type(8))) short short8;
typedef __attribute__((ext_vector_type(4))) float floatx4;

#define HWPIX 16384
#define IMG 128

__device__ __forceinline__ float b2f(u16 u) {
    unsigned int x = ((unsigned int)u) << 16;
    return __builtin_bit_cast(float, x);
}
__device__ __forceinline__ u16 f2b(float f) {
    __hip_bfloat16 h = __float2bfloat16(f);
    return __builtin_bit_cast(u16, h);
}

// bf16 weight cache: [wmap 131072][wk 65536][wq 65536][wv 65536]
__device__ __align__(16) u16 g_w16[327680];

__global__ __launch_bounds__(256)
void wconv_kernel(const float* __restrict__ wmap, const float* __restrict__ wq,
                  const float* __restrict__ wk, const float* __restrict__ wv)
{
    int i = blockIdx.x * 256 + threadIdx.x;
    const float* src; int off;
    if (i < 131072)      { src = wmap; off = i; }
    else if (i < 196608) { src = wk;   off = i - 131072; }
    else if (i < 262144) { src = wq;   off = i - 196608; }
    else                 { src = wv;   off = i - 262144; }
    g_w16[i] = f2b(src[off]);
}

// ---------------------------------------------------------------------------
// fused qkv: per 32-px tile, stage X=[noisy;aux] bf16 in LDS once, then
//   v    = Wv  @ X[0:256]          -> vmap
//   naux = relu(Wmap @ X + bias)   -> LDS (never touches global!)
//   k    = Wk @ naux               -> kmap
//   q    = 0.125 * Wq @ naux       -> qmap
// Weights are read as A-fragments DIRECTLY from global (bf16, L2-resident,
// 16B/lane contiguous) — no A staging, no nv round-trip, 2 barriers total.
// ---------------------------------------------------------------------------
__global__ __launch_bounds__(256, 2)
void fused_qkv_kernel(const float* __restrict__ noisy, const float* __restrict__ aux,
                      const float* __restrict__ bias,
                      u16* __restrict__ qmap, u16* __restrict__ kmap,
                      u16* __restrict__ vmap)
{
    __shared__ u16 Xlds[32 * 520];      // [px][ch 0..511], stride 520 (1040B ≡ 16 mod 128)
    __shared__ u16 Nlds[32 * 264];      // naux [px][ch 0..255], stride 264
    __shared__ float BiasL[256];

    const int tid = threadIdx.x;
    const int wave = tid >> 6, lane = tid & 63;
    const int quad = lane >> 4, l16 = lane & 15;
    const int px0 = blockIdx.x * 32;
    const int b = blockIdx.z;
    const int wmo = wave * 64;          // each wave owns 64 output channels

    // ---- stage bias + X (all global loads issued up front, one latency hit)
    float bvv = bias[tid];
    const int ch0 = 2 * tid, ch1 = 2 * tid + 1;
    const float* s0 = (ch0 < 256 ? noisy : aux) + ((size_t)b * 256 + (ch0 & 255)) * HWPIX + px0;
    const float* s1 = (ch1 < 256 ? noisy : aux) + ((size_t)b * 256 + (ch1 & 255)) * HWPIX + px0;
    float4 f0[8], f1[8];
#pragma unroll
    for (int j = 0; j < 8; ++j) {
        f0[j] = ((const float4*)s0)[j];
        f1[j] = ((const float4*)s1)[j];
    }
    BiasL[tid] = bvv;
#pragma unroll
    for (int j = 0; j < 8; ++j) {
        float p0[4] = {f0[j].x, f0[j].y, f0[j].z, f0[j].w};
        float p1[4] = {f1[j].x, f1[j].y, f1[j].z, f1[j].w};
#pragma unroll
        for (int i = 0; i < 4; ++i) {
            int px = j * 4 + i;
            unsigned w = (unsigned)f2b(p0[i]) | ((unsigned)f2b(p1[i]) << 16);
            // lanes span ch-pairs -> dword = tid + const -> 2-way banks (free)
            *(unsigned*)&Xlds[px * 520 + ch0] = w;
        }
    }
    __syncthreads();

    // ---- common GEMM pass: A from global bf16 (row-major MxK), B from LDS
    auto run_gemm = [&](const u16* __restrict__ Wg, int Kw, const u16* __restrict__ Bsrc,
                        int ldb, int nks, floatx4 (&acc)[4][2]) {
#pragma unroll
        for (int mi = 0; mi < 4; ++mi)
#pragma unroll
            for (int pj = 0; pj < 2; ++pj) acc[mi][pj] = (floatx4){0.f, 0.f, 0.f, 0.f};
        for (int ks = 0; ks < nks; ++ks) {
            const int c0 = ks * 32;
            short8 bf[2];
#pragma unroll
            for (int pj = 0; pj < 2; ++pj)
                bf[pj] = *(const short8*)&Bsrc[(pj * 16 + l16) * ldb + c0 + quad * 8];
#pragma unroll
            for (int mi = 0; mi < 4; ++mi) {
                short8 af = *(const short8*)&Wg[(size_t)(wmo + mi * 16 + l16) * Kw + c0 + quad * 8];
#pragma unroll
                for (int pj = 0; pj < 2; ++pj)
                    acc[mi][pj] = __builtin_amdgcn_mfma_f32_16x16x32_bf16(af, bf[pj], acc[mi][pj], 0, 0, 0);
            }
        }
    };
    auto store_out = [&](floatx4 (&acc)[4][2], u16* __restrict__ dst, float scale) {
#pragma unroll
        for (int mi = 0; mi < 4; ++mi)
#pragma unroll
            for (int pj = 0; pj < 2; ++pj)
#pragma unroll
                for (int r = 0; r < 4; ++r) {
                    int ch = wmo + mi * 16 + quad * 4 + r;
                    dst[((size_t)b * 256 + ch) * HWPIX + px0 + pj * 16 + l16] =
                        f2b(acc[mi][pj][r] * scale);
                }
    };

    floatx4 acc[4][2];

    // ---- v = Wv @ noisy-half of X
    run_gemm(g_w16 + 262144, 256, Xlds, 520, 8, acc);
    store_out(acc, vmap, 1.f);

    // ---- naux = relu(Wmap @ X + bias) -> LDS
    run_gemm(g_w16, 512, Xlds, 520, 16, acc);
#pragma unroll
    for (int mi = 0; mi < 4; ++mi)
#pragma unroll
        for (int pj = 0; pj < 2; ++pj)
#pragma unroll
            for (int r = 0; r < 4; ++r) {
                int ch = wmo + mi * 16 + quad * 4 + r;        // BiasL[ch]: l16-uniform -> broadcast
                float v = fmaxf(acc[mi][pj][r] + BiasL[ch], 0.f);
                Nlds[(pj * 16 + l16) * 264 + ch] = f2b(v);
            }
    __syncthreads();

    // ---- k = Wk @ naux ; q = 0.125 * Wq @ naux
    run_gemm(g_w16 + 131072, 256, Nlds, 264, 8, acc);
    store_out(acc, kmap, 1.f);
    run_gemm(g_w16 + 196608, 256, Nlds, 264, 8, acc);
    store_out(acc, qmap, 0.125f);
}

// V^T LDS swizzle. Row stride 512B (multiple of 128B so the XOR is a
// bijection WITHIN the row: colByte<512, XOR touches bits 4-8 only).
__device__ __forceinline__ int vswz(int dd, int colByte) {
    return dd * 512 + (colByte ^ ((dd & 31) << 4));
}

// ---------------------------------------------------------------------------
// attention: one workgroup per (b, bh, bw, head). Q 64x64, K/V 196x64 (pad 224)
// ---------------------------------------------------------------------------
__global__ __launch_bounds__(256)
void attn_kernel(const u16* __restrict__ qmap, const u16* __restrict__ kmap,
                 const u16* __restrict__ vmap, const float* __restrict__ relh,
                 const float* __restrict__ relw, float* __restrict__ out)
{
    __shared__ u16 Qlds[64 * 72];    // [qpos][dd]; reused as O[dd][qpos]
    __shared__ u16 Klds[224 * 72];   // [kpos][dd]; reused as S[qpos][232]
    __shared__ u16 Vlds[64 * 256];   // V^T: [dd][kpos], XOR-swizzled (vswz)
    __shared__ float RelHf[448], RelWf[448];

    const int tid = threadIdx.x;
    const int wave = tid >> 6, lane = tid & 63;
    const int quad = lane >> 4, l16 = lane & 15;
    char* Vb = (char*)Vlds;

    const int n = blockIdx.x + 16 * blockIdx.y + 256 * blockIdx.z;
    const int n2 = (n & 7) * 512 + (n >> 3);
    const int bw = n2 & 15, bh = (n2 >> 4) & 15;
    const int head = (n2 >> 8) & 3, b = n2 >> 10;

    const size_t chbase = ((size_t)b * 256 + head * 64) * HWPIX;

    // ================= phase 0: issue ALL global loads (no waits) ==========
    float rh0 = relh[tid], rw0 = relw[tid];
    float rh1 = 0.f, rw1 = 0.f;
    if (tid < 192) { rh1 = relh[tid + 256]; rw1 = relw[tid + 256]; }

    const u16* qrow = qmap + chbase + (size_t)lane * HWPIX + bw * 8;
    uint4 q0 = *(const uint4*)(qrow + (bh * 8 + wave) * IMG);
    uint4 q1 = *(const uint4*)(qrow + (bh * 8 + wave + 4) * IMG);

    const int cbyte = min(max(bw * 16 - 8, 0), 224);
    uint2 kseg[4][4], vseg[4][4];
#pragma unroll
    for (int s = 0; s < 4; ++s) {
        if (s < 3 || wave < 2) {
            const int wr = wave + 4 * s;
            const int ih = bh * 8 - 3 + wr;
            const int ihc = min(max(ih, 0), 127);
            const char* kp = (const char*)(kmap + chbase + (size_t)lane * HWPIX) + ihc * 256 + cbyte;
            const char* vp = (const char*)(vmap + chbase + (size_t)lane * HWPIX) + ihc * 256 + cbyte;
#pragma unroll
            for (int j = 0; j < 4; ++j) {
                kseg[s][j] = *(const uint2*)(kp + 8 * j);
                vseg[s][j] = *(const uint2*)(vp + 8 * j);
            }
        }
    }

    // ================= phase 1: rel + Q -> LDS =============================
    RelHf[tid] = rh0; RelWf[tid] = rw0;
    if (tid < 192) { RelHf[tid + 256] = rh1; RelWf[tid + 256] = rw1; }
    {
        union { uint4 v; u16 s[8]; } t0, t1;
        t0.v = q0; t1.v = q1;
#pragma unroll
        for (int i = 0; i < 8; ++i) {
            Qlds[(wave * 8 + i) * 72 + lane] = t0.s[i];
            Qlds[((wave + 4) * 8 + i) * 72 + lane] = t1.s[i];
        }
    }
    __syncthreads();

    // ================= phase 2: K(+rel), V^T -> LDS; pad ===================
    const int iwb = bw * 8 - 3;
#pragma unroll
    for (int s = 0; s < 4; ++s) {
        if (s < 3 || wave < 2) {
            const int wr = wave + 4 * s;
            const int ih = bh * 8 - 3 + wr;
            const bool rok = (unsigned)ih < 128u;
            union { uint2 v[4]; u16 u[16]; } kr, vr;
#pragma unroll
            for (int j = 0; j < 4; ++j) { kr.v[j] = kseg[s][j]; vr.v[j] = vseg[s][j]; }
            if (bw == 0) {
#pragma unroll
                for (int i = 15; i >= 4; --i) { kr.u[i] = kr.u[i - 4]; vr.u[i] = vr.u[i - 4]; }
            } else if (bw == 15) {
#pragma unroll
                for (int i = 0; i < 12; ++i) { kr.u[i] = kr.u[i + 4]; vr.u[i] = vr.u[i + 4]; }
            }
            const int kb = wr * 14;
            u16 vm[14];
#pragma unroll
            for (int sc = 0; sc < 14; ++sc) {
                const bool ok = rok && ((unsigned)(iwb + sc) < 128u);
                vm[sc] = ok ? vr.u[sc + 1] : (u16)0;
                const float kv = ok ? b2f(kr.u[sc + 1]) : 0.f;
                const float rel = (lane < 32) ? RelHf[wr * 32 + (lane & 31)]
                                              : RelWf[sc * 32 + (lane & 31)];
                Klds[(kb + sc) * 72 + lane] = f2b(kv + rel);
            }
#pragma unroll
            for (int p = 0; p < 7; ++p)
                *(unsigned*)(Vb + vswz(lane, kb * 2 + p * 4)) =
                    (unsigned)vm[2 * p] | ((unsigned)vm[2 * p + 1] << 16);
        }
    }
    for (int t = tid; t < 28 * 64; t += 256) {
        int kp_ = 196 + (t >> 6), ch = t & 63;
        Klds[kp_ * 72 + ch] = 0;
        *(u16*)(Vb + vswz(ch, kp_ * 2)) = 0;
    }
    __syncthreads();

    // ---- sim = Q K^T
    floatx4 sacc[14];
#pragma unroll
    for (int f = 0; f < 14; ++f) sacc[f] = (floatx4){0.f, 0.f, 0.f, 0.f};
    __builtin_amdgcn_s_setprio(1);
#pragma unroll
    for (int kc = 0; kc < 2; ++kc) {
        short8 qa = *(const short8*)&Qlds[(wave * 16 + l16) * 72 + kc * 32 + quad * 8];
#pragma unroll
        for (int f = 0; f < 14; ++f) {
            short8 kb = *(const short8*)&Klds[(f * 16 + l16) * 72 + kc * 32 + quad * 8];
            sacc[f] = __builtin_amdgcn_mfma_f32_16x16x32_bf16(qa, kb, sacc[f], 0, 0, 0);
        }
    }
    __builtin_amdgcn_s_setprio(0);

    // ---- softmax
    float pm[14][4], rmax[4], rsum[4];
#pragma unroll
    for (int r = 0; r < 4; ++r) rmax[r] = -3.0e4f;
#pragma unroll
    for (int f = 0; f < 14; ++f) {
        int col = f * 16 + l16;
#pragma unroll
        for (int r = 0; r < 4; ++r) {
            float v = (col < 196) ? sacc[f][r] : -3.0e4f;
            pm[f][r] = v;
            rmax[r] = fmaxf(rmax[r], v);
        }
    }
#pragma unroll
    for (int off = 1; off < 16; off <<= 1)
#pragma unroll
        for (int r = 0; r < 4; ++r)
            rmax[r] = fmaxf(rmax[r], __shfl_xor(rmax[r], off, 64));
#pragma unroll
    for (int r = 0; r < 4; ++r) rsum[r] = 0.f;
#pragma unroll
    for (int f = 0; f < 14; ++f)
#pragma unroll
        for (int r = 0; r < 4; ++r) {
            float e = __expf(pm[f][r] - rmax[r]);
            pm[f][r] = e;
            rsum[r] += e;
        }
#pragma unroll
    for (int off = 1; off < 16; off <<= 1)
#pragma unroll
        for (int r = 0; r < 4; ++r)
            rsum[r] += __shfl_xor(rsum[r], off, 64);
    float rinv[4];
#pragma unroll
    for (int r = 0; r < 4; ++r) rinv[r] = 1.f / rsum[r];

    __syncthreads();

    // ---- P (bf16) into S = Klds region, [qpos][232]
    u16* S = Klds;
#pragma unroll
    for (int f = 0; f < 14; ++f)
#pragma unroll
        for (int r = 0; r < 4; ++r)
            S[(wave * 16 + quad * 4 + r) * 232 + f * 16 + l16] = f2b(pm[f][r] * rinv[r]);
    __syncthreads();

    // ---- out = P V
    floatx4 oacc[4];
#pragma unroll
    for (int f = 0; f < 4; ++f) oacc[f] = (floatx4){0.f, 0.f, 0.f, 0.f};
    __builtin_amdgcn_s_setprio(1);
#pragma unroll
    for (int kc = 0; kc < 7; ++kc) {
        short8 pa = *(const short8*)&S[(wave * 16 + l16) * 232 + kc * 32 + quad * 8];
#pragma unroll
        for (int f = 0; f < 4; ++f) {
            short8 vb = *(const short8*)(Vb + vswz(f * 16 + l16, kc * 64 + quad * 16));
            oacc[f] = __builtin_amdgcn_mfma_f32_16x16x32_bf16(pa, vb, oacc[f], 0, 0, 0);
        }
    }
    __builtin_amdgcn_s_setprio(0);

    // ---- transpose O through Qlds region (O[dd][qpos], stride 72)
    u16* O = Qlds;
#pragma unroll
    for (int f = 0; f < 4; ++f)
#pragma unroll
        for (int r = 0; r < 4; ++r)
            O[(f * 16 + l16) * 72 + wave * 16 + quad * 4 + r] = f2b(oacc[f][r]);
    __syncthreads();

    // ---- fp32 output stores
    for (int t = tid; t < 512; t += 256) {
        int ch = t >> 3, r = t & 7;
        const u16* src = &O[ch * 72 + r * 8];
        float4 v0 = {b2f(src[0]), b2f(src[1]), b2f(src[2]), b2f(src[3])};
        float4 v1 = {b2f(src[4]), b2f(src[5]), b2f(src[6]), b2f(src[7])};
        float* dst = out + chbase + ch * HWPIX + (bh * 8 + r) * IMG + bw * 8;
        *(float4*)dst = v0;
        *(float4*)(dst + 4) = v1;
    }
}

extern "C" void kernel_launch(void* const* d_in, const int* in_sizes, int n_in,
                              void* d_out, int out_size, void* d_ws, size_t ws_size,
                              hipStream_t stream)
{
    (void)in_sizes; (void)n_in; (void)out_size; (void)ws_size;
    const float* noisy = (const float*)d_in[0];
    const float* aux   = (const float*)d_in[1];
    const float* w_map = (const float*)d_in[2];
    const float* b_map = (const float*)d_in[3];
    const float* w_q   = (const float*)d_in[4];
    const float* w_k   = (const float*)d_in[5];
    const float* w_v   = (const float*)d_in[6];
    const float* rel_h = (const float*)d_in[7];
    const float* rel_w = (const float*)d_in[8];
    float* out = (float*)d_out;

    // ws layout (96 MiB): [vmap 32MiB][kmap 32MiB][qmap 32MiB]
    u16* vmap = (u16*)d_ws;
    u16* kmap = vmap + (size_t)16777216;
    u16* qmap = kmap + (size_t)16777216;

    wconv_kernel<<<1280, 256, 0, stream>>>(w_map, w_q, w_k, w_v);
    fused_qkv_kernel<<<dim3(512, 1, 4), 256, 0, stream>>>(noisy, aux, b_map, qmap, kmap, vmap);
    attn_kernel<<<dim3(16, 16, 16), 256, 0, stream>>>(qmap, kmap, vmap, rel_h, rel_w, out);
}